// Round 10
// baseline (200.706 us; speedup 1.0000x reference)
//
#include <hip/hip_runtime.h>
#include <math.h>

// ---------------------------------------------------------------------------
// SphericalConvCodec. fp64 decision path (encoder + exact rescore) matches the
// fp64 numpy reference. VQ: ONE fused kernel -- each block owns 64 queries and
// scans the whole codebook twice (phase 1: global f16 max in-wave, no atomics;
// phase 2: rescore candidates >= max - DELTA exactly in fp64). Decoder fp32.
// codebook = d_in[13] (dict-literal order puts it after decoder weights).
// ws layout (byte offsets):
#define WSB_Q64   0u         // 32768*12 double  (3145728 B)
#define WSB_QZ    3145728u   // 32768*12 float
#define WSB_KEYS  4718592u   // 32768 u64        (262144 B)
#define WSB_CCH   4980736u   // 8192 double      (65536 B)
#define WSB_W1D   5046272u   // 64 double
#define WSB_W2D   5046784u   // 2048 double [k][o][c]
#define WSB_W3D   5063168u   // 1536 double [q][j][o]
#define WSB_B1D   5075456u   // 16 double
#define WSB_B2D   5075584u   // 32 double
#define WSB_B3D   5075840u   // 12 double
#define WSB_D1R   5075936u   // 1536 float [p][o][c]
#define WSB_D2R   5082080u   // 2048 float [k][o][c]
#define WSB_D3R   5090272u   // 64 float  [k][c]
#define WSB_CB16  5090528u   // 8192*16 _Float16, FRAGMENT-ORDERED [tile][half][col][8]
#define WSB_Q16   5352672u   // 32768*16 _Float16 (1048576 B)
#define DELTA 0.003f
#define SCALE46 70368744177664.0  // 2^46

typedef _Float16 half8 __attribute__((ext_vector_type(8)));
typedef float f32x16 __attribute__((ext_vector_type(16)));

__device__ __forceinline__ float relu(float v) { return v > 0.f ? v : 0.f; }

// ---------------------------------------------------------------------------
// prep: zero keys; cchalf fp64; cb16 fragment-ordered; block 0 repacks
__global__ __launch_bounds__(256) void k_prep(
    const float* __restrict__ w1, const float* __restrict__ b1,
    const float* __restrict__ w2, const float* __restrict__ b2,
    const float* __restrict__ w3, const float* __restrict__ b3,
    const float* __restrict__ cbk, const float* __restrict__ d1w,
    const float* __restrict__ d2w, const float* __restrict__ d3w,
    unsigned long long* __restrict__ keys, double* __restrict__ cch,
    double* __restrict__ w1d, double* __restrict__ w2d,
    double* __restrict__ w3d, double* __restrict__ b1d,
    double* __restrict__ b2d, double* __restrict__ b3d,
    float* __restrict__ d1r, float* __restrict__ d2r,
    float* __restrict__ d3r, _Float16* __restrict__ cb16) {
  int gid = blockIdx.x * 256 + threadIdx.x;  // grid 128 -> 32768
  keys[gid] = 0ull;
  if (gid < 8192) {
    double s = 0.0;
    half8 lo, hi;
#pragma unroll
    for (int d = 0; d < 12; d++) {
      float cf = cbk[gid * 12 + d];
      double c = (double)cf;
      s = fma(c, c, s);
      if (d < 8) lo[d] = (_Float16)cf; else hi[d - 8] = (_Float16)cf;
    }
#pragma unroll
    for (int d = 4; d < 8; d++) hi[d] = (_Float16)0.f;
    cch[gid] = 0.5 * s;
    // fragment order: tile = code>>5, col = code&31; half k-slice contiguous
    int tile = gid >> 5, col = gid & 31;
    *(half8*)(cb16 + (size_t)(tile * 64 + col) * 8) = lo;        // half 0
    *(half8*)(cb16 + (size_t)(tile * 64 + 32 + col) * 8) = hi;   // half 1
  }
  if (blockIdx.x == 0) {
    int t = threadIdx.x;
    for (int i = t; i < 64; i += 256) w1d[i] = (double)w1[i];
    for (int i = t; i < 16; i += 256) b1d[i] = (double)b1[i];
    for (int i = t; i < 32; i += 256) b2d[i] = (double)b2[i];
    for (int i = t; i < 12; i += 256) b3d[i] = (double)b3[i];
    for (int i = t; i < 2048; i += 256) {  // w2d[k][o][c] = w2[o][c][k]
      int k = i >> 9, o = (i >> 4) & 31, c = i & 15;
      w2d[i] = (double)w2[o * 64 + c * 4 + k];
    }
    for (int i = t; i < 1536; i += 256) {  // w3d[q][j][o] = w3[j][o][q]
      int q = i / 384, r = i % 384, j = r >> 5, o = r & 31;
      w3d[i] = (double)w3[j * 128 + o * 4 + q];
    }
    for (int i = t; i < 1536; i += 256) {  // d1r[p][o][c] = d1w[c][o][p]
      int p = i / 384, r = i % 384, o = r / 12, c = r % 12;
      d1r[i] = d1w[c * 128 + o * 4 + p];
    }
    for (int i = t; i < 2048; i += 256) {  // d2r[k][o][c] = d2w[c][o][k]
      int k = i >> 9, o = (i >> 5) & 15, c = i & 31;
      d2r[i] = d2w[c * 64 + o * 4 + k];
    }
    for (int i = t; i < 64; i += 256) {    // d3r[k][c] = d3w[c][k]
      int k = i >> 4, c = i & 15;
      d3r[i] = d3w[c * 4 + k];
    }
  }
}

// ---------------------------------------------------------------------------
// encoder, fp64 (unchanged from passing round 9): block = 512 = 8 waves,
// wave = (quarter qq, o-half oh); weights staged in LDS; (512,2) VGPR cap.
__global__ __launch_bounds__(512, 2) void k_enc(
    const float* __restrict__ x, const double* __restrict__ w1d,
    const double* __restrict__ w2d, const double* __restrict__ w3d,
    const double* __restrict__ b1d, const double* __restrict__ b2d,
    const double* __restrict__ b3d, float* __restrict__ cont_out,
    double* __restrict__ q64out, _Float16* __restrict__ q16out) {
  __shared__ double w2s[2048];
  __shared__ double w3s[1536];
  __shared__ double w1s[64];
  __shared__ double b1s[16], b2s[32], b3s[12];
  __shared__ double red[8][64][12];

  int t = threadIdx.x;
  for (int i = t; i < 2048; i += 512) w2s[i] = w2d[i];
  for (int i = t; i < 1536; i += 512) w3s[i] = w3d[i];
  if (t < 64) w1s[t] = w1d[t];
  else if (t >= 64 && t < 80) b1s[t - 64] = b1d[t - 64];
  else if (t >= 80 && t < 112) b2s[t - 80] = b2d[t - 80];
  else if (t >= 112 && t < 124) b3s[t - 112] = b3d[t - 112];
  __syncthreads();

  int w = t >> 6, lane = t & 63;
  int qq = w & 3, oh = w >> 2;
  int win = blockIdx.x * 64 + lane;
  int n = win >> 4, l = win & 15;
  const float* xb = x + n * 1024 + l * 64 + qq * 16;

  double h2[16];
#pragma unroll
  for (int o = 0; o < 16; o++) h2[o] = b2s[oh * 16 + o];

#pragma unroll 1
  for (int k = 0; k < 4; k++) {
    float4 xv = *reinterpret_cast<const float4*>(xb + 4 * k);
    double x0 = (double)xv.x, x1 = (double)xv.y;
    double x2 = (double)xv.z, x3 = (double)xv.w;
    double h1[16];
#pragma unroll
    for (int c = 0; c < 16; c++) {
      const double* wv = w1s + 4 * c;
      double s = b1s[c];
      s = fma(x0, wv[0], s); s = fma(x1, wv[1], s);
      s = fma(x2, wv[2], s); s = fma(x3, wv[3], s);
      h1[c] = s > 0.0 ? s : 0.0;
    }
    const double* w2k = w2s + k * 512 + oh * 256;
#pragma unroll
    for (int o = 0; o < 16; o++) {
      const double* wp = w2k + o * 16;
      double s = h2[o];
#pragma unroll
      for (int c = 0; c < 16; c++) s = fma(h1[c], wp[c], s);
      h2[o] = s;
    }
  }
#pragma unroll
  for (int o = 0; o < 16; o++) h2[o] = h2[o] > 0.0 ? h2[o] : 0.0;

  const double* w3q = w3s + qq * 384 + oh * 16;
#pragma unroll
  for (int j = 0; j < 12; j++) {
    const double* wp = w3q + j * 32;
    double s = 0.0;
#pragma unroll
    for (int o = 0; o < 16; o++) s = fma(h2[o], wp[o], s);
    red[w][lane][j] = s;
  }
  __syncthreads();

  if (w == 0) {
    double cont[12], ss = 0.0;
#pragma unroll
    for (int j = 0; j < 12; j++) {
      double v = b3s[j] +
          (((red[0][lane][j] + red[1][lane][j]) +
            (red[2][lane][j] + red[3][lane][j])) +
           ((red[4][lane][j] + red[5][lane][j]) +
            (red[6][lane][j] + red[7][lane][j])));
      cont[j] = v;
      ss = fma(v, v, ss);
    }
    double nrm = sqrt(ss);
    if (nrm < 1e-12) nrm = 1e-12;
    half8 lo, hi;
#pragma unroll
    for (int j = 0; j < 12; j++) {
      double qv = cont[j] / nrm;
      float qf = (float)qv;
      cont_out[n * 192 + j * 16 + l] = qf;
      q64out[(size_t)win * 12 + j] = qv;
      if (j < 8) lo[j] = (_Float16)qf; else hi[j - 8] = (_Float16)qf;
    }
#pragma unroll
    for (int j = 4; j < 8; j++) hi[j] = (_Float16)0.f;
    *(half8*)(q16out + (size_t)win * 16) = lo;
    *(half8*)(q16out + (size_t)win * 16 + 8) = hi;
  }
}

// ---------------------------------------------------------------------------
// fused VQ: block = 2 waves x 32 queries = 64 queries, grid 512 (2 blocks/CU).
// Loops over 8x 1024-code chunks, double-buffered 32 KB LDS staged with
// global_load_lds width-16 (global fragment order == LDS layout, linear copy;
// loads issued before compute, drained at the barrier).
// Phase 1 (steps 0-7): branch-free fmax scan -> in-wave global max (shfl).
// Phase 2 (steps 8-15): cndmask candidate mask, one rare branch per tile,
// inline exact fp64 rescore (identical fma chain/key/tie-break as passing).
// D layout: col=lane&31, row=(reg&3)+8*(reg>>2)+4*(lane>>5)  [m74/m101]
__global__ __launch_bounds__(128) void k_vq(
    const _Float16* __restrict__ q16, const _Float16* __restrict__ cbf,
    const double* __restrict__ q64, const float* __restrict__ cbk,
    const double* __restrict__ cchalf,
    unsigned long long* __restrict__ keys) {
  __shared__ __align__(16) _Float16 cb[2][16384];  // 2 x 32 KB
  int t = threadIdx.x;
  int wave = t >> 6, lane = t & 63;
  int half = lane >> 5, col = lane & 31;
  int qbase = blockIdx.x * 64 + wave * 32;

  half8 a = *(const half8*)(q16 + (size_t)(qbase + col) * 16 + half * 8);
  f32x16 z = {0.f, 0.f, 0.f, 0.f, 0.f, 0.f, 0.f, 0.f,
              0.f, 0.f, 0.f, 0.f, 0.f, 0.f, 0.f, 0.f};

  // stage chunk cc into buffer buf: per wave 16 KB = 16 x 1 KB instructions
#define STAGE(buf, cc)                                                        \
  {                                                                           \
    const char* sbase = (const char*)cbf + (size_t)(cc)*32768 +               \
                        wave * 16384 + lane * 16;                             \
    char* dbase = (char*)&cb[(buf)][0] + wave * 16384;                        \
    _Pragma("unroll") for (int i = 0; i < 16; i++) {                          \
      __builtin_amdgcn_global_load_lds(                                       \
          (const unsigned int*)(sbase + i * 1024),                            \
          (unsigned int*)(dbase + i * 1024), 16, 0, 0);                       \
    }                                                                         \
  }

  float mx[16];
#pragma unroll
  for (int r = 0; r < 16; r++) mx[r] = -3.f;

  STAGE(0, 0);
  __syncthreads();

  // ---- phase 1: global f16 max per query ----
#pragma unroll 1
  for (int step = 0; step < 8; step++) {
    STAGE((step + 1) & 1, (step + 1) & 7);  // step 7 stages chunk 0 for ph2
    const _Float16* cbb = &cb[step & 1][0];
#pragma unroll 4
    for (int tt = 0; tt < 32; tt++) {
      half8 b = *(const half8*)(cbb + (tt * 64 + lane) * 8);
      f32x16 d = __builtin_amdgcn_mfma_f32_32x32x16_f16(a, b, z, 0, 0, 0);
#pragma unroll
      for (int r = 0; r < 16; r++) mx[r] = fmaxf(mx[r], d[r]);
    }
    __syncthreads();
  }

  // column reduce (xor masks <=16 stay within each 32-lane half); thr = mx-D
#pragma unroll
  for (int m = 1; m <= 16; m <<= 1) {
#pragma unroll
    for (int r = 0; r < 16; r++) mx[r] = fmaxf(mx[r], __shfl_xor(mx[r], m));
  }
  float thr[16];
#pragma unroll
  for (int r = 0; r < 16; r++) thr[r] = mx[r] - DELTA;

  // ---- phase 2: candidate mask + exact fp64 rescore ----
#pragma unroll 1
  for (int step = 8; step < 16; step++) {
    if (step < 15) STAGE((step + 1) & 1, (step + 1) & 7);
    int cc = step & 7;
    const _Float16* cbb = &cb[step & 1][0];
#pragma unroll 2
    for (int tt = 0; tt < 32; tt++) {
      half8 b = *(const half8*)(cbb + (tt * 64 + lane) * 8);
      f32x16 d = __builtin_amdgcn_mfma_f32_32x32x16_f16(a, b, z, 0, 0, 0);
      unsigned msk = 0u;
#pragma unroll
      for (int r = 0; r < 16; r++)
        msk |= (d[r] >= thr[r]) ? (1u << r) : 0u;
      if (msk) {
#pragma unroll
        for (int r = 0; r < 16; r++) {
          if (msk & (1u << r)) {
            unsigned row = (r & 3) + 8 * (r >> 2) + 4 * half;
            int q = qbase + row;
            int c = cc * 1024 + tt * 32 + col;
            const double* qp = q64 + (size_t)q * 12;
            const float* cp = cbk + c * 12;
            double s = 0.0;
#pragma unroll
            for (int dd = 0; dd < 12; dd++)
              s = fma(qp[dd], (double)cp[dd], s);
            unsigned long long ek =
                (unsigned long long)((s - cchalf[c] + 2.0) * SCALE46);
            atomicMax(&keys[q], (ek << 16) | (unsigned)(8191 - c));
          }
        }
      }
    }
    if (step < 15) __syncthreads();
  }
#undef STAGE
}

// ---------------------------------------------------------------------------
// unpack: key -> idx -> gather codebook row
__global__ __launch_bounds__(256) void k_unpack(
    const unsigned long long* __restrict__ keys,
    const float* __restrict__ codebook, float* __restrict__ quant_out,
    float* __restrict__ qz) {
  int q = blockIdx.x * 256 + threadIdx.x;  // grid 128 -> 32768
  int gidx = 8191 - (int)(keys[q] & 0xFFFFull);
  int n = q >> 4, l = q & 15;
  const float* cp = codebook + gidx * 12;
#pragma unroll
  for (int c = 0; c < 12; c++) {
    float v = cp[c];
    quant_out[n * 192 + c * 16 + l] = v;
    qz[q * 12 + c] = v;
  }
}

// ---------------------------------------------------------------------------
// decoder (fp32): wave = deconv1 sub-position, lane = window
__global__ __launch_bounds__(256) void k_dec(
    const float* __restrict__ qz, const float* __restrict__ d1r,
    const float* __restrict__ d2r, const float* __restrict__ d3r,
    const float* __restrict__ d1b, const float* __restrict__ d2b,
    const float* __restrict__ d3b, float* __restrict__ rec) {
  int t = threadIdx.x;
  int p2 = t >> 6, lane = t & 63;
  int win = blockIdx.x * 64 + lane;  // grid 512 -> 32768
  const float4* qp = reinterpret_cast<const float4*>(qz + win * 12);
  float4 q0 = qp[0], q1 = qp[1], q2 = qp[2];

  const float* d1p = d1r + p2 * 384;
  float y1[32];
#pragma unroll
  for (int o = 0; o < 32; o++) {
    const float4* wp = reinterpret_cast<const float4*>(d1p + o * 12);
    float4 a0 = wp[0], a1 = wp[1], a2 = wp[2];
    float s = d1b[o];
    s = fmaf(q0.x, a0.x, s); s = fmaf(q0.y, a0.y, s);
    s = fmaf(q0.z, a0.z, s); s = fmaf(q0.w, a0.w, s);
    s = fmaf(q1.x, a1.x, s); s = fmaf(q1.y, a1.y, s);
    s = fmaf(q1.z, a1.z, s); s = fmaf(q1.w, a1.w, s);
    s = fmaf(q2.x, a2.x, s); s = fmaf(q2.y, a2.y, s);
    s = fmaf(q2.z, a2.z, s); s = fmaf(q2.w, a2.w, s);
    y1[o] = relu(s);
  }

  float d3bias = d3b[0];
#pragma unroll 1
  for (int k = 0; k < 4; k++) {
    const float* d2k = d2r + k * 512;
    float y2[16];
#pragma unroll
    for (int o = 0; o < 16; o++) {
      const float4* wp = reinterpret_cast<const float4*>(d2k + o * 32);
      float s = d2b[o];
#pragma unroll
      for (int g = 0; g < 8; g++) {
        float4 a = wp[g];
        s = fmaf(y1[4 * g + 0], a.x, s); s = fmaf(y1[4 * g + 1], a.y, s);
        s = fmaf(y1[4 * g + 2], a.z, s); s = fmaf(y1[4 * g + 3], a.w, s);
      }
      y2[o] = relu(s);
    }
    float ov[4];
#pragma unroll
    for (int kk = 0; kk < 4; kk++) {
      const float4* wp = reinterpret_cast<const float4*>(d3r + kk * 16);
      float s = d3bias;
#pragma unroll
      for (int g = 0; g < 4; g++) {
        float4 a = wp[g];
        s = fmaf(y2[4 * g + 0], a.x, s); s = fmaf(y2[4 * g + 1], a.y, s);
        s = fmaf(y2[4 * g + 2], a.z, s); s = fmaf(y2[4 * g + 3], a.w, s);
      }
      ov[kk] = s;
    }
    *reinterpret_cast<float4*>(rec + win * 64 + p2 * 16 + k * 4) =
        make_float4(ov[0], ov[1], ov[2], ov[3]);
  }
}

// ---------------------------------------------------------------------------
extern "C" void kernel_launch(void* const* d_in, const int* in_sizes, int n_in,
                              void* d_out, int out_size, void* d_ws,
                              size_t ws_size, hipStream_t stream) {
  const float* x  = (const float*)d_in[0];
  const float* w1 = (const float*)d_in[1];
  const float* b1 = (const float*)d_in[2];
  const float* w2 = (const float*)d_in[3];
  const float* b2 = (const float*)d_in[4];
  const float* w3 = (const float*)d_in[5];
  const float* b3 = (const float*)d_in[6];
  int cb_idx = (in_sizes[13] == 98304) ? 13 : 7;
  int dbase = (cb_idx == 13) ? 7 : 8;
  const float* cbk = (const float*)d_in[cb_idx];
  const float* d1w = (const float*)d_in[dbase + 0];
  const float* d1b = (const float*)d_in[dbase + 1];
  const float* d2w = (const float*)d_in[dbase + 2];
  const float* d2b = (const float*)d_in[dbase + 3];
  const float* d3w = (const float*)d_in[dbase + 4];
  const float* d3b = (const float*)d_in[dbase + 5];

  float* out = (float*)d_out;
  float* rec = out;                 // (2048,1,1024)
  float* cont_out = out + 2097152;  // (2048,12,16)
  float* quant_out = out + 2490368; // (2048,12,16)

  char* wsb = (char*)d_ws;
  double* q64 = (double*)(wsb + WSB_Q64);
  float* qz = (float*)(wsb + WSB_QZ);
  unsigned long long* keys = (unsigned long long*)(wsb + WSB_KEYS);
  double* cch = (double*)(wsb + WSB_CCH);
  double* w1d = (double*)(wsb + WSB_W1D);
  double* w2d = (double*)(wsb + WSB_W2D);
  double* w3d = (double*)(wsb + WSB_W3D);
  double* b1d = (double*)(wsb + WSB_B1D);
  double* b2d = (double*)(wsb + WSB_B2D);
  double* b3d = (double*)(wsb + WSB_B3D);
  float* d1r = (float*)(wsb + WSB_D1R);
  float* d2r = (float*)(wsb + WSB_D2R);
  float* d3r = (float*)(wsb + WSB_D3R);
  _Float16* cb16 = (_Float16*)(wsb + WSB_CB16);
  _Float16* q16 = (_Float16*)(wsb + WSB_Q16);

  k_prep<<<128, 256, 0, stream>>>(w1, b1, w2, b2, w3, b3, cbk, d1w, d2w, d3w,
                                  keys, cch, w1d, w2d, w3d, b1d, b2d, b3d,
                                  d1r, d2r, d3r, cb16);
  k_enc<<<512, 512, 0, stream>>>(x, w1d, w2d, w3d, b1d, b2d, b3d, cont_out,
                                 q64, q16);
  k_vq<<<512, 128, 0, stream>>>(q16, cb16, q64, cbk, cch, keys);
  k_unpack<<<128, 256, 0, stream>>>(keys, cbk, quant_out, qz);
  k_dec<<<512, 256, 0, stream>>>(qz, d1r, d2r, d3r, d1b, d2b, d3b, rec);
}

// Round 11
// 171.841 us; speedup vs baseline: 1.1680x; 1.1680x over previous
//
#include <hip/hip_runtime.h>
#include <math.h>

// ---------------------------------------------------------------------------
// SphericalConvCodec. fp64 decision path (encoder + exact rescore) matches the
// fp64 numpy reference; VQ scan uses f16 MFMA (32x32x16): kernel 1 computes the
// per-query GLOBAL max (distributed atomicMax), kernel 2 re-scans and rescores
// candidates >= max - DELTA inline in fp64. Round 10's fused version dropped to
// 1 wave/SIMD (10% occupancy) -> latency-bound; two kernels with CBC=512 and
// 4096 blocks give 16K waves. Decoder fp32.
// codebook = d_in[13] (dict-literal order puts it after decoder weights).
// ws layout (byte offsets):
#define WSB_Q64   0u         // 32768*12 double  (3145728 B)
#define WSB_QZ    3145728u   // 32768*12 float; qmax u32[32768] overlaps (disjoint lifetime)
#define WSB_KEYS  4718592u   // 32768 u64        (262144 B)
#define WSB_CCH   4980736u   // 8192 double      (65536 B)
#define WSB_W1D   5046272u   // 64 double
#define WSB_W2D   5046784u   // 2048 double [k][o][c]
#define WSB_W3D   5063168u   // 1536 double [q][j][o]
#define WSB_B1D   5075456u   // 16 double
#define WSB_B2D   5075584u   // 32 double
#define WSB_B3D   5075840u   // 12 double
#define WSB_D1R   5075936u   // 1536 float [p][o][c]
#define WSB_D2R   5082080u   // 2048 float [k][o][c]
#define WSB_D3R   5090272u   // 64 float  [k][c]
#define WSB_CB16  5090528u   // 8192*16 _Float16, FRAGMENT-ORDERED [tile][half][col][8]
#define WSB_Q16   5352672u   // 32768*16 _Float16 (1048576 B)
#define DELTA 0.003f
#define SCALE46 70368744177664.0  // 2^46
#define CBC 512               // codes per VQ chunk (16 KB LDS -> occupancy!)

typedef _Float16 half8 __attribute__((ext_vector_type(8)));
typedef float f32x16 __attribute__((ext_vector_type(16)));

__device__ __forceinline__ float relu(float v) { return v > 0.f ? v : 0.f; }

// monotone float<->uint order transform (valid for all finite floats)
__device__ __forceinline__ unsigned okey(float s) {
  unsigned u = __float_as_uint(s);
  return u ^ ((u & 0x80000000u) ? 0xFFFFFFFFu : 0x80000000u);
}
__device__ __forceinline__ float unokey(unsigned k) {
  unsigned u = k ^ ((k & 0x80000000u) ? 0x80000000u : 0xFFFFFFFFu);
  return __uint_as_float(u);
}

// ---------------------------------------------------------------------------
// prep: zero keys+qmax; cchalf fp64; cb16 fragment-ordered; block 0 repacks
__global__ __launch_bounds__(256) void k_prep(
    const float* __restrict__ w1, const float* __restrict__ b1,
    const float* __restrict__ w2, const float* __restrict__ b2,
    const float* __restrict__ w3, const float* __restrict__ b3,
    const float* __restrict__ cbk, const float* __restrict__ d1w,
    const float* __restrict__ d2w, const float* __restrict__ d3w,
    unsigned long long* __restrict__ keys, unsigned* __restrict__ qmax,
    double* __restrict__ cch,
    double* __restrict__ w1d, double* __restrict__ w2d,
    double* __restrict__ w3d, double* __restrict__ b1d,
    double* __restrict__ b2d, double* __restrict__ b3d,
    float* __restrict__ d1r, float* __restrict__ d2r,
    float* __restrict__ d3r, _Float16* __restrict__ cb16) {
  int gid = blockIdx.x * 256 + threadIdx.x;  // grid 128 -> 32768
  keys[gid] = 0ull;
  qmax[gid] = 0u;   // < okey(-3): any real score beats this
  if (gid < 8192) {
    double s = 0.0;
    half8 lo, hi;
#pragma unroll
    for (int d = 0; d < 12; d++) {
      float cf = cbk[gid * 12 + d];
      double c = (double)cf;
      s = fma(c, c, s);
      if (d < 8) lo[d] = (_Float16)cf; else hi[d - 8] = (_Float16)cf;
    }
#pragma unroll
    for (int d = 4; d < 8; d++) hi[d] = (_Float16)0.f;
    cch[gid] = 0.5 * s;
    // fragment order: tile = code>>5, col = code&31; half k-slice contiguous
    int tile = gid >> 5, col = gid & 31;
    *(half8*)(cb16 + (size_t)(tile * 64 + col) * 8) = lo;        // half 0
    *(half8*)(cb16 + (size_t)(tile * 64 + 32 + col) * 8) = hi;   // half 1
  }
  if (blockIdx.x == 0) {
    int t = threadIdx.x;
    for (int i = t; i < 64; i += 256) w1d[i] = (double)w1[i];
    for (int i = t; i < 16; i += 256) b1d[i] = (double)b1[i];
    for (int i = t; i < 32; i += 256) b2d[i] = (double)b2[i];
    for (int i = t; i < 12; i += 256) b3d[i] = (double)b3[i];
    for (int i = t; i < 2048; i += 256) {  // w2d[k][o][c] = w2[o][c][k]
      int k = i >> 9, o = (i >> 4) & 31, c = i & 15;
      w2d[i] = (double)w2[o * 64 + c * 4 + k];
    }
    for (int i = t; i < 1536; i += 256) {  // w3d[q][j][o] = w3[j][o][q]
      int q = i / 384, r = i % 384, j = r >> 5, o = r & 31;
      w3d[i] = (double)w3[j * 128 + o * 4 + q];
    }
    for (int i = t; i < 1536; i += 256) {  // d1r[p][o][c] = d1w[c][o][p]
      int p = i / 384, r = i % 384, o = r / 12, c = r % 12;
      d1r[i] = d1w[c * 128 + o * 4 + p];
    }
    for (int i = t; i < 2048; i += 256) {  // d2r[k][o][c] = d2w[c][o][k]
      int k = i >> 9, o = (i >> 5) & 15, c = i & 31;
      d2r[i] = d2w[c * 64 + o * 4 + k];
    }
    for (int i = t; i < 64; i += 256) {    // d3r[k][c] = d3w[c][k]
      int k = i >> 4, c = i & 15;
      d3r[i] = d3w[c * 4 + k];
    }
  }
}

// ---------------------------------------------------------------------------
// encoder, fp64 (unchanged from passing round 9): block = 512 = 8 waves,
// wave = (quarter qq, o-half oh); weights staged in LDS; (512,2) VGPR cap.
__global__ __launch_bounds__(512, 2) void k_enc(
    const float* __restrict__ x, const double* __restrict__ w1d,
    const double* __restrict__ w2d, const double* __restrict__ w3d,
    const double* __restrict__ b1d, const double* __restrict__ b2d,
    const double* __restrict__ b3d, float* __restrict__ cont_out,
    double* __restrict__ q64out, _Float16* __restrict__ q16out) {
  __shared__ double w2s[2048];
  __shared__ double w3s[1536];
  __shared__ double w1s[64];
  __shared__ double b1s[16], b2s[32], b3s[12];
  __shared__ double red[8][64][12];

  int t = threadIdx.x;
  for (int i = t; i < 2048; i += 512) w2s[i] = w2d[i];
  for (int i = t; i < 1536; i += 512) w3s[i] = w3d[i];
  if (t < 64) w1s[t] = w1d[t];
  else if (t >= 64 && t < 80) b1s[t - 64] = b1d[t - 64];
  else if (t >= 80 && t < 112) b2s[t - 80] = b2d[t - 80];
  else if (t >= 112 && t < 124) b3s[t - 112] = b3d[t - 112];
  __syncthreads();

  int w = t >> 6, lane = t & 63;
  int qq = w & 3, oh = w >> 2;
  int win = blockIdx.x * 64 + lane;
  int n = win >> 4, l = win & 15;
  const float* xb = x + n * 1024 + l * 64 + qq * 16;

  double h2[16];
#pragma unroll
  for (int o = 0; o < 16; o++) h2[o] = b2s[oh * 16 + o];

#pragma unroll 1
  for (int k = 0; k < 4; k++) {
    float4 xv = *reinterpret_cast<const float4*>(xb + 4 * k);
    double x0 = (double)xv.x, x1 = (double)xv.y;
    double x2 = (double)xv.z, x3 = (double)xv.w;
    double h1[16];
#pragma unroll
    for (int c = 0; c < 16; c++) {
      const double* wv = w1s + 4 * c;
      double s = b1s[c];
      s = fma(x0, wv[0], s); s = fma(x1, wv[1], s);
      s = fma(x2, wv[2], s); s = fma(x3, wv[3], s);
      h1[c] = s > 0.0 ? s : 0.0;
    }
    const double* w2k = w2s + k * 512 + oh * 256;
#pragma unroll
    for (int o = 0; o < 16; o++) {
      const double* wp = w2k + o * 16;
      double s = h2[o];
#pragma unroll
      for (int c = 0; c < 16; c++) s = fma(h1[c], wp[c], s);
      h2[o] = s;
    }
  }
#pragma unroll
  for (int o = 0; o < 16; o++) h2[o] = h2[o] > 0.0 ? h2[o] : 0.0;

  const double* w3q = w3s + qq * 384 + oh * 16;
#pragma unroll
  for (int j = 0; j < 12; j++) {
    const double* wp = w3q + j * 32;
    double s = 0.0;
#pragma unroll
    for (int o = 0; o < 16; o++) s = fma(h2[o], wp[o], s);
    red[w][lane][j] = s;
  }
  __syncthreads();

  if (w == 0) {
    double cont[12], ss = 0.0;
#pragma unroll
    for (int j = 0; j < 12; j++) {
      double v = b3s[j] +
          (((red[0][lane][j] + red[1][lane][j]) +
            (red[2][lane][j] + red[3][lane][j])) +
           ((red[4][lane][j] + red[5][lane][j]) +
            (red[6][lane][j] + red[7][lane][j])));
      cont[j] = v;
      ss = fma(v, v, ss);
    }
    double nrm = sqrt(ss);
    if (nrm < 1e-12) nrm = 1e-12;
    half8 lo, hi;
#pragma unroll
    for (int j = 0; j < 12; j++) {
      double qv = cont[j] / nrm;
      float qf = (float)qv;
      cont_out[n * 192 + j * 16 + l] = qf;
      q64out[(size_t)win * 12 + j] = qv;
      if (j < 8) lo[j] = (_Float16)qf; else hi[j - 8] = (_Float16)qf;
    }
#pragma unroll
    for (int j = 4; j < 8; j++) hi[j] = (_Float16)0.f;
    *(half8*)(q16out + (size_t)win * 16) = lo;
    *(half8*)(q16out + (size_t)win * 16 + 8) = hi;
  }
}

// ---------------------------------------------------------------------------
// VQ pass 1: per-query GLOBAL max of f16 scores via distributed atomicMax.
// Block: 4 waves x 32 queries = 128 queries, one 512-code chunk in 16 KB LDS.
// grid = 256 qg x 16 cc = 4096 blocks (16K waves -> occupancy).
// D layout: col=lane&31, row=(reg&3)+8*(reg>>2)+4*(lane>>5)  [m74/m101]
__global__ __launch_bounds__(256) void k_vq1(
    const _Float16* __restrict__ q16, const _Float16* __restrict__ cbf,
    unsigned* __restrict__ qmax) {
  __shared__ _Float16 cb[CBC * 16];  // 16 KB
  int t = threadIdx.x;
  int qg = blockIdx.x >> 4;  // 256 query groups of 128
  int cc = blockIdx.x & 15;  // 16 code chunks of 512
  {
    const float4* src = (const float4*)(cbf + (size_t)cc * CBC * 16);
    float4* dst = (float4*)cb;
#pragma unroll
    for (int i = 0; i < CBC * 16 / 8 / 256; i++)
      dst[t + i * 256] = src[t + i * 256];
  }
  __syncthreads();

  int wave = t >> 6, lane = t & 63;
  int half = lane >> 5, col = lane & 31;
  int qbase = qg * 128 + wave * 32;
  half8 a = *(const half8*)(q16 + (size_t)(qbase + col) * 16 + half * 8);
  f32x16 z = {0.f, 0.f, 0.f, 0.f, 0.f, 0.f, 0.f, 0.f,
              0.f, 0.f, 0.f, 0.f, 0.f, 0.f, 0.f, 0.f};
  float mx[16];
#pragma unroll
  for (int r = 0; r < 16; r++) mx[r] = -3.f;

#pragma unroll 4
  for (int tt = 0; tt < CBC / 32; tt++) {
    half8 b = *(const half8*)(cb + (tt * 64 + lane) * 8);
    f32x16 d = __builtin_amdgcn_mfma_f32_32x32x16_f16(a, b, z, 0, 0, 0);
#pragma unroll
    for (int r = 0; r < 16; r++) mx[r] = fmaxf(mx[r], d[r]);
  }
  // reduce across 32 columns (xor masks <=16 stay within each 32-half)
#pragma unroll
  for (int m = 1; m <= 16; m <<= 1) {
#pragma unroll
    for (int r = 0; r < 16; r++) mx[r] = fmaxf(mx[r], __shfl_xor(mx[r], m));
  }
  // lane col==r (one per half) publishes row max; addresses all distinct
#pragma unroll
  for (int r = 0; r < 16; r++) {
    if (col == r) {
      unsigned row = (r & 3) + 8 * (r >> 2) + 4 * half;
      atomicMax(&qmax[qbase + row], okey(mx[r]));
    }
  }
}

// ---------------------------------------------------------------------------
// VQ pass 2: re-scan; any d >= global_max - DELTA is rescored EXACTLY in fp64
// (identical fma chain/key/tie-break as the round-3 passing kernel) and merged
// via atomicMax over 32768 distributed keys. The f16-argmax always triggers,
// so every query gets >=1 key. ~45K candidates total -> negligible.
__global__ __launch_bounds__(256) void k_vq2(
    const _Float16* __restrict__ q16, const _Float16* __restrict__ cbf,
    const unsigned* __restrict__ qmax, const double* __restrict__ q64,
    const float* __restrict__ cbk, const double* __restrict__ cchalf,
    unsigned long long* __restrict__ keys) {
  __shared__ _Float16 cb[CBC * 16];  // 16 KB
  int t = threadIdx.x;
  int qg = blockIdx.x >> 4;
  int cc = blockIdx.x & 15;
  {
    const float4* src = (const float4*)(cbf + (size_t)cc * CBC * 16);
    float4* dst = (float4*)cb;
#pragma unroll
    for (int i = 0; i < CBC * 16 / 8 / 256; i++)
      dst[t + i * 256] = src[t + i * 256];
  }
  __syncthreads();

  int wave = t >> 6, lane = t & 63;
  int half = lane >> 5, col = lane & 31;
  int qbase = qg * 128 + wave * 32;
  half8 a = *(const half8*)(q16 + (size_t)(qbase + col) * 16 + half * 8);
  f32x16 z = {0.f, 0.f, 0.f, 0.f, 0.f, 0.f, 0.f, 0.f,
              0.f, 0.f, 0.f, 0.f, 0.f, 0.f, 0.f, 0.f};

  float thr[16];
#pragma unroll
  for (int r = 0; r < 16; r++) {
    unsigned row = (r & 3) + 8 * (r >> 2) + 4 * half;
    thr[r] = unokey(qmax[qbase + row]) - DELTA;
  }

#pragma unroll 2
  for (int tt = 0; tt < CBC / 32; tt++) {
    half8 b = *(const half8*)(cb + (tt * 64 + lane) * 8);
    f32x16 d = __builtin_amdgcn_mfma_f32_32x32x16_f16(a, b, z, 0, 0, 0);
    unsigned msk = 0u;
#pragma unroll
    for (int r = 0; r < 16; r++)
      msk |= (d[r] >= thr[r]) ? (1u << r) : 0u;
    if (msk) {
#pragma unroll
      for (int r = 0; r < 16; r++) {
        if (msk & (1u << r)) {
          unsigned row = (r & 3) + 8 * (r >> 2) + 4 * half;
          int q = qbase + row;
          int c = cc * CBC + tt * 32 + col;
          const double* qp = q64 + (size_t)q * 12;
          const float* cp = cbk + c * 12;
          double s = 0.0;
#pragma unroll
          for (int dd = 0; dd < 12; dd++)
            s = fma(qp[dd], (double)cp[dd], s);
          unsigned long long ek =
              (unsigned long long)((s - cchalf[c] + 2.0) * SCALE46);
          atomicMax(&keys[q], (ek << 16) | (unsigned)(8191 - c));
        }
      }
    }
  }
}

// ---------------------------------------------------------------------------
// unpack: key -> idx -> gather codebook row
__global__ __launch_bounds__(256) void k_unpack(
    const unsigned long long* __restrict__ keys,
    const float* __restrict__ codebook, float* __restrict__ quant_out,
    float* __restrict__ qz) {
  int q = blockIdx.x * 256 + threadIdx.x;  // grid 128 -> 32768
  int gidx = 8191 - (int)(keys[q] & 0xFFFFull);
  int n = q >> 4, l = q & 15;
  const float* cp = codebook + gidx * 12;
#pragma unroll
  for (int c = 0; c < 12; c++) {
    float v = cp[c];
    quant_out[n * 192 + c * 16 + l] = v;
    qz[q * 12 + c] = v;
  }
}

// ---------------------------------------------------------------------------
// decoder (fp32): wave = deconv1 sub-position, lane = window
__global__ __launch_bounds__(256) void k_dec(
    const float* __restrict__ qz, const float* __restrict__ d1r,
    const float* __restrict__ d2r, const float* __restrict__ d3r,
    const float* __restrict__ d1b, const float* __restrict__ d2b,
    const float* __restrict__ d3b, float* __restrict__ rec) {
  int t = threadIdx.x;
  int p2 = t >> 6, lane = t & 63;
  int win = blockIdx.x * 64 + lane;  // grid 512 -> 32768
  const float4* qp = reinterpret_cast<const float4*>(qz + win * 12);
  float4 q0 = qp[0], q1 = qp[1], q2 = qp[2];

  const float* d1p = d1r + p2 * 384;
  float y1[32];
#pragma unroll
  for (int o = 0; o < 32; o++) {
    const float4* wp = reinterpret_cast<const float4*>(d1p + o * 12);
    float4 a0 = wp[0], a1 = wp[1], a2 = wp[2];
    float s = d1b[o];
    s = fmaf(q0.x, a0.x, s); s = fmaf(q0.y, a0.y, s);
    s = fmaf(q0.z, a0.z, s); s = fmaf(q0.w, a0.w, s);
    s = fmaf(q1.x, a1.x, s); s = fmaf(q1.y, a1.y, s);
    s = fmaf(q1.z, a1.z, s); s = fmaf(q1.w, a1.w, s);
    s = fmaf(q2.x, a2.x, s); s = fmaf(q2.y, a2.y, s);
    s = fmaf(q2.z, a2.z, s); s = fmaf(q2.w, a2.w, s);
    y1[o] = relu(s);
  }

  float d3bias = d3b[0];
#pragma unroll 1
  for (int k = 0; k < 4; k++) {
    const float* d2k = d2r + k * 512;
    float y2[16];
#pragma unroll
    for (int o = 0; o < 16; o++) {
      const float4* wp = reinterpret_cast<const float4*>(d2k + o * 32);
      float s = d2b[o];
#pragma unroll
      for (int g = 0; g < 8; g++) {
        float4 a = wp[g];
        s = fmaf(y1[4 * g + 0], a.x, s); s = fmaf(y1[4 * g + 1], a.y, s);
        s = fmaf(y1[4 * g + 2], a.z, s); s = fmaf(y1[4 * g + 3], a.w, s);
      }
      y2[o] = relu(s);
    }
    float ov[4];
#pragma unroll
    for (int kk = 0; kk < 4; kk++) {
      const float4* wp = reinterpret_cast<const float4*>(d3r + kk * 16);
      float s = d3bias;
#pragma unroll
      for (int g = 0; g < 4; g++) {
        float4 a = wp[g];
        s = fmaf(y2[4 * g + 0], a.x, s); s = fmaf(y2[4 * g + 1], a.y, s);
        s = fmaf(y2[4 * g + 2], a.z, s); s = fmaf(y2[4 * g + 3], a.w, s);
      }
      ov[kk] = s;
    }
    *reinterpret_cast<float4*>(rec + win * 64 + p2 * 16 + k * 4) =
        make_float4(ov[0], ov[1], ov[2], ov[3]);
  }
}

// ---------------------------------------------------------------------------
extern "C" void kernel_launch(void* const* d_in, const int* in_sizes, int n_in,
                              void* d_out, int out_size, void* d_ws,
                              size_t ws_size, hipStream_t stream) {
  const float* x  = (const float*)d_in[0];
  const float* w1 = (const float*)d_in[1];
  const float* b1 = (const float*)d_in[2];
  const float* w2 = (const float*)d_in[3];
  const float* b2 = (const float*)d_in[4];
  const float* w3 = (const float*)d_in[5];
  const float* b3 = (const float*)d_in[6];
  int cb_idx = (in_sizes[13] == 98304) ? 13 : 7;
  int dbase = (cb_idx == 13) ? 7 : 8;
  const float* cbk = (const float*)d_in[cb_idx];
  const float* d1w = (const float*)d_in[dbase + 0];
  const float* d1b = (const float*)d_in[dbase + 1];
  const float* d2w = (const float*)d_in[dbase + 2];
  const float* d2b = (const float*)d_in[dbase + 3];
  const float* d3w = (const float*)d_in[dbase + 4];
  const float* d3b = (const float*)d_in[dbase + 5];

  float* out = (float*)d_out;
  float* rec = out;                 // (2048,1,1024)
  float* cont_out = out + 2097152;  // (2048,12,16)
  float* quant_out = out + 2490368; // (2048,12,16)

  char* wsb = (char*)d_ws;
  double* q64 = (double*)(wsb + WSB_Q64);
  float* qz = (float*)(wsb + WSB_QZ);
  unsigned* qmax = (unsigned*)(wsb + WSB_QZ);  // overlap: lifetime disjoint
  unsigned long long* keys = (unsigned long long*)(wsb + WSB_KEYS);
  double* cch = (double*)(wsb + WSB_CCH);
  double* w1d = (double*)(wsb + WSB_W1D);
  double* w2d = (double*)(wsb + WSB_W2D);
  double* w3d = (double*)(wsb + WSB_W3D);
  double* b1d = (double*)(wsb + WSB_B1D);
  double* b2d = (double*)(wsb + WSB_B2D);
  double* b3d = (double*)(wsb + WSB_B3D);
  float* d1r = (float*)(wsb + WSB_D1R);
  float* d2r = (float*)(wsb + WSB_D2R);
  float* d3r = (float*)(wsb + WSB_D3R);
  _Float16* cb16 = (_Float16*)(wsb + WSB_CB16);
  _Float16* q16 = (_Float16*)(wsb + WSB_Q16);

  k_prep<<<128, 256, 0, stream>>>(w1, b1, w2, b2, w3, b3, cbk, d1w, d2w, d3w,
                                  keys, qmax, cch, w1d, w2d, w3d, b1d, b2d,
                                  b3d, d1r, d2r, d3r, cb16);
  k_enc<<<512, 512, 0, stream>>>(x, w1d, w2d, w3d, b1d, b2d, b3d, cont_out,
                                 q64, q16);
  k_vq1<<<4096, 256, 0, stream>>>(q16, cb16, qmax);
  k_vq2<<<4096, 256, 0, stream>>>(q16, cb16, qmax, q64, cbk, cch, keys);
  k_unpack<<<128, 256, 0, stream>>>(keys, cbk, quant_out, qz);
  k_dec<<<512, 256, 0, stream>>>(qz, d1r, d2r, d3r, d1b, d2b, d3b, rec);
}